// Round 13
// baseline (197.891 us; speedup 1.0000x reference)
//
#include <hip/hip_runtime.h>

// ---------------------------------------------------------------------------
// MultiHeadedAttention: B=2, S=2048, Dm=1024, H=16, hd=64
// R16: GEMM pipeline fix (gemm_qkv is now the top kernel, 49.7us @ 516 TF):
//  - both GEMMs switch from the 2-barrier stage->drain->compute loop to
//    double-buffered prefetch-ahead-1 with ONE barrier per K-step
//    (T3-minimum / m248 2-phase recipe): STAGE(t+1) issues before compute(t)
//    -> staging latency hides under MFMA instead of being serially exposed
//  - compute bodies, staging addressing, V-fragment epilogue byte-identical
//  - prep / attn_fused13 byte-identical to R15 (verified)
// ---------------------------------------------------------------------------

typedef __bf16 bf16x8 __attribute__((ext_vector_type(8)));
typedef __bf16 bf16x4 __attribute__((ext_vector_type(4)));
typedef short s16x4 __attribute__((ext_vector_type(4)));
typedef float f32x4 __attribute__((ext_vector_type(4)));
typedef int i32x2 __attribute__((ext_vector_type(2)));

#define B_   2
#define S_   2048
#define DM   1024
#define NH   16
#define HD   64
#define N3   3072
#define M_   4096   // B_*S_

// 0.125 (1/sqrt(64)) * log2(e) -- folded into W_in Q-columns on host side
#define SCALE_LOG2E 0.180336884f

__device__ __forceinline__ unsigned short f2bf(float f) {
  unsigned int u = __float_as_uint(f);
  u += 0x7fffu + ((u >> 16) & 1u);   // round-to-nearest-even
  return (unsigned short)(u >> 16);
}

__device__ __forceinline__ void gload_lds16(void* lds, const void* g) {
  __builtin_amdgcn_global_load_lds(
      (__attribute__((address_space(1))) void*)g,
      (__attribute__((address_space(3))) void*)lds, 16, 0, 0);
}

// 16x16x16 bf16 MFMA: builtin name differs across ROCm versions
__device__ __forceinline__ f32x4 mfma16(bf16x4 a, bf16x4 b, f32x4 c) {
#if __has_builtin(__builtin_amdgcn_mfma_f32_16x16x16_bf16)
  return __builtin_amdgcn_mfma_f32_16x16x16_bf16(a, b, c, 0, 0, 0);
#else
  return __builtin_amdgcn_mfma_f32_16x16x16bf16_1k(
      __builtin_bit_cast(s16x4, a), __builtin_bit_cast(s16x4, b), c, 0, 0, 0);
#endif
}

// packed f32 pair -> bf16x2 in one VALU op (RTNE), lo=s0 hi=s1
__device__ __forceinline__ int cvtpk(float s0, float s1) {
  int r;
  asm("v_cvt_pk_bf16_f32 %0, %1, %2" : "=v"(r) : "v"(s0), "v"(s1));
  return r;
}

// ---------------- prep: qbf convert + both weight transposes ---------------
// grid 8192 x 256thr: [0,4096) qbf; [4096,7168) w_in^T (scaled); rest w_out^T
__global__ __launch_bounds__(256) void prep(
    const float* __restrict__ query, const float* __restrict__ w_in,
    const float* __restrict__ w_out, unsigned short* __restrict__ qbf,
    unsigned short* __restrict__ w_in_t, unsigned short* __restrict__ w_out_t) {
  __shared__ float tile[32][33];
  const int bx = blockIdx.x;
  const int t = threadIdx.x;
  if (bx < 4096) {                       // query f32 -> bf16, 1024 elems/block
    const int i = bx * 256 + t;
    const float4 v = ((const float4*)query)[i];
    ushort4 o;
    o.x = f2bf(v.x); o.y = f2bf(v.y); o.z = f2bf(v.z); o.w = f2bf(v.w);
    *(ushort4*)(&qbf[(size_t)i * 4]) = o;
    return;
  }
  // 32x32 transpose tasks (tx = t&31, ty = t>>5; 8 rows per pass)
  const int tx = t & 31, ty = t >> 5;
  const float* in;
  unsigned short* out;
  int R, C, bxx, bxy, scale_rows;
  if (bx < 4096 + 3072) {                // w_in [1024][3072] -> [3072][1024]
    const int id = bx - 4096;
    in = w_in; out = w_in_t; R = DM; C = N3;
    bxx = id % 96; bxy = id / 96; scale_rows = DM;
  } else {                               // w_out [1024][1024] -> [1024][1024]
    const int id = bx - 7168;
    in = w_out; out = w_out_t; R = DM; C = DM;
    bxx = id & 31; bxy = id >> 5; scale_rows = 0;
  }
  const int x = bxx * 32 + tx;
  const int y0 = bxy * 32;
#pragma unroll
  for (int j = 0; j < 32; j += 8)
    tile[ty + j][tx] = in[(size_t)(y0 + ty + j) * C + x];
  __syncthreads();
  const int ox = y0 + tx;
  const int oy0 = bxx * 32;
#pragma unroll
  for (int j = 0; j < 32; j += 8) {
    const int orow = oy0 + ty + j;
    float v = tile[tx][ty + j];
    if (orow < scale_rows) v *= SCALE_LOG2E;
    out[(size_t)orow * R + ox] = f2bf(v);
  }
}

// ------- GEMM1: qkv = A @ Bt^T; V-slice written in vTn fragment layout -----
// Double-buffered prefetch-ahead-1, one barrier per K-step (T3-minimum).
// C cols [0,2048) -> qkv row-major bf16 (Q,K). Cols [2048,3072) -> vTn.
__global__ __launch_bounds__(256) void gemm_qkv(
    const unsigned short* __restrict__ A, const unsigned short* __restrict__ Bt,
    unsigned short* __restrict__ qkv, unsigned short* __restrict__ vTn) {
  __shared__ __align__(16) unsigned short a_sm[2][128 * 32];
  __shared__ __align__(16) unsigned short b_sm[2][128 * 32];
  const int tid = threadIdx.x;
  const int lane = tid & 63, wave = tid >> 6;
  const int quad = lane >> 4, l15 = lane & 15;
  const int row0 = blockIdx.y * 128, col0 = blockIdx.x * 128;
  const int wm = (wave >> 1) * 64, wn = (wave & 1) * 64;
  const int K = DM;
  const int NK = K / 32;

  f32x4 acc[4][4];
#pragma unroll
  for (int i = 0; i < 4; i++)
#pragma unroll
    for (int j = 0; j < 4; j++) acc[i][j] = (f32x4){0.f, 0.f, 0.f, 0.f};

  const int e0 = tid * 8;

  // stage K-tile kt (32 wide) into buffer bi
  auto STAGE = [&](int kt, int bi) {
    const int k0 = kt * 32;
#pragma unroll
    for (int i = 0; i < 2; i++) {
      int e = e0 + i * 2048;
      int r = e >> 5, c = e & 31;
      gload_lds16(&a_sm[bi][e], &A[(size_t)(row0 + r) * K + k0 + c]);
      gload_lds16(&b_sm[bi][e], &Bt[(size_t)(col0 + r) * K + k0 + c]);
    }
  };

  STAGE(0, 0);
  asm volatile("s_waitcnt vmcnt(0)" ::: "memory");
  __builtin_amdgcn_s_barrier();

  for (int kt = 0; kt < NK; kt++) {
    const int cur = kt & 1;
    if (kt + 1 < NK) STAGE(kt + 1, cur ^ 1);

    bf16x8 af[4], bfb[4];
#pragma unroll
    for (int i = 0; i < 4; i++) {
      af[i]  = *(const bf16x8*)&a_sm[cur][(wm + i * 16 + l15) * 32 + quad * 8];
      bfb[i] = *(const bf16x8*)&b_sm[cur][(wn + i * 16 + l15) * 32 + quad * 8];
    }
    __builtin_amdgcn_s_setprio(1);
#pragma unroll
    for (int i = 0; i < 4; i++)
#pragma unroll
      for (int j = 0; j < 4; j++)
        acc[i][j] = __builtin_amdgcn_mfma_f32_16x16x32_bf16(af[i], bfb[j], acc[i][j], 0, 0, 0);
    __builtin_amdgcn_s_setprio(0);

    if (kt + 1 < NK) {
      asm volatile("s_waitcnt vmcnt(0)" ::: "memory");
      __builtin_amdgcn_s_barrier();
    }
  }

  if (col0 + wn < 2 * DM) {
    // Q/K slices: row-major bf16 into qkv
#pragma unroll
    for (int i = 0; i < 4; i++) {
#pragma unroll
      for (int j = 0; j < 4; j++) {
#pragma unroll
        for (int r = 0; r < 4; r++) {
          const int row = row0 + wm + i * 16 + quad * 4 + r;
          const int col = col0 + wn + j * 16 + l15;
          qkv[(size_t)row * N3 + col] = f2bf(acc[i][j][r]);
        }
      }
    }
  } else {
    // V slice: write vTn fragment layout directly (one ushort4 per (i,j))
    const int head = (col0 + wn - 2 * DM) >> 6;   // wave-uniform
#pragma unroll
    for (int i = 0; i < 4; i++) {
      const int row = row0 + wm + i * 16 + quad * 4;   // token of r=0
      const int b = row >> 11;
      const int srow = row & 2047;
      const int kt = srow >> 6;
      const int s = srow & 63;
      const int p = s >> 5, half = (s >> 4) & 1, q = (s >> 2) & 3;
      const size_t base = (size_t)((b * NH + head) * 32 + kt) * 4096;
#pragma unroll
      for (int j = 0; j < 4; j++) {
        const int d = j * 16 + l15;
        ushort4 w;
        w.x = f2bf(acc[i][j][0]);
        w.y = f2bf(acc[i][j][1]);
        w.z = f2bf(acc[i][j][2]);
        w.w = f2bf(acc[i][j][3]);
        *(ushort4*)&vTn[base + (size_t)(p * 256 + d * 4 + q) * 8 + half * 4] = w;
      }
    }
  }
}

// ---------------- GEMM 64x128 (fp32 out), dbuf prefetch-ahead-1 ------------
// grid (N/128, M/64), 256 threads. Wave w: rows 0..63, cols w*32..+31.
__global__ __launch_bounds__(256) void gemm_abt_64(
    const unsigned short* __restrict__ A, const unsigned short* __restrict__ Bt,
    float* __restrict__ C, int M, int N, int K) {
  __shared__ __align__(16) unsigned short a_sm[2][64 * 32];    // 8KB
  __shared__ __align__(16) unsigned short b_sm[2][128 * 32];   // 16KB
  const int tid = threadIdx.x;
  const int lane = tid & 63, wave = tid >> 6;
  const int quad = lane >> 4, l15 = lane & 15;
  const int row0 = blockIdx.y * 64, col0 = blockIdx.x * 128;
  const int wn = wave * 32;
  const int NK = K / 32;

  f32x4 acc[4][2];
#pragma unroll
  for (int i = 0; i < 4; i++)
#pragma unroll
    for (int j = 0; j < 2; j++) acc[i][j] = (f32x4){0.f, 0.f, 0.f, 0.f};

  const int e0 = tid * 8;

  auto STAGE = [&](int kt, int bi) {
    const int k0 = kt * 32;
    {
      const int r = e0 >> 5, c = e0 & 31;
      gload_lds16(&a_sm[bi][e0], &A[(size_t)(row0 + r) * K + k0 + c]);
    }
#pragma unroll
    for (int i = 0; i < 2; i++) {
      int e = e0 + i * 2048;
      int r = e >> 5, c = e & 31;
      gload_lds16(&b_sm[bi][e], &Bt[(size_t)(col0 + r) * K + k0 + c]);
    }
  };

  STAGE(0, 0);
  asm volatile("s_waitcnt vmcnt(0)" ::: "memory");
  __builtin_amdgcn_s_barrier();

  for (int kt = 0; kt < NK; kt++) {
    const int cur = kt & 1;
    if (kt + 1 < NK) STAGE(kt + 1, cur ^ 1);

    bf16x8 af[4], bfb[2];
#pragma unroll
    for (int i = 0; i < 4; i++)
      af[i] = *(const bf16x8*)&a_sm[cur][(i * 16 + l15) * 32 + quad * 8];
#pragma unroll
    for (int j = 0; j < 2; j++)
      bfb[j] = *(const bf16x8*)&b_sm[cur][(wn + j * 16 + l15) * 32 + quad * 8];
    __builtin_amdgcn_s_setprio(1);
#pragma unroll
    for (int i = 0; i < 4; i++)
#pragma unroll
      for (int j = 0; j < 2; j++)
        acc[i][j] = __builtin_amdgcn_mfma_f32_16x16x32_bf16(af[i], bfb[j], acc[i][j], 0, 0, 0);
    __builtin_amdgcn_s_setprio(0);

    if (kt + 1 < NK) {
      asm volatile("s_waitcnt vmcnt(0)" ::: "memory");
      __builtin_amdgcn_s_barrier();
    }
  }

#pragma unroll
  for (int i = 0; i < 4; i++) {
#pragma unroll
    for (int j = 0; j < 2; j++) {
#pragma unroll
      for (int r = 0; r < 4; r++) {
        const int row = row0 + i * 16 + quad * 4 + r;
        const int col = col0 + wn + j * 16 + l15;
        C[(size_t)row * N + col] = acc[i][j][r];
      }
    }
  }
}

// ---------------- fused causal attention v13 (R15-verified) ----------------
// grid (16, NH, B) = 512 blocks, 512 threads (8 waves).
// T1 chunked XCD swizzle; KVBLK=128 rounds; 4 LDS buffers; prefetch
// distance 1 round; vmcnt(0) + raw s_barrier per round.
__global__ __launch_bounds__(512, 4) void attn_fused13(
    const unsigned short* __restrict__ qkv,
    const unsigned short* __restrict__ vTn,
    unsigned short* __restrict__ attnout) {
  // chunked XCD swizzle (bijective: 512 blocks = 8 XCD x 64)
  const int p = blockIdx.x + (blockIdx.y << 4) + (blockIdx.z << 8);
  const int lg = ((p & 7) << 6) + (p >> 3);
  const int j = lg & 15;
  const int h = (lg >> 4) & 15;
  const int b = lg >> 8;

  const int tid = threadIdx.x;
  const int lane = tid & 63, wave = tid >> 6;   // wave 0..7
  const int quad = lane >> 4, l15 = lane & 15;
  const int sw = l15 & 7;

  __shared__ __align__(16) unsigned short k_sm[4 * 4096];   // [buf][64 keys][64 d]
  __shared__ __align__(16) unsigned short vt_sm[4 * 4096];  // [buf][512 x 16B units]

  // wave 0..3 -> low q-tile (rows j*64 ..); wave 4..7 -> high tile ((31-j)*64 ..)
  const int wrow0 = (wave < 4) ? (j * 64 + wave * 16)
                               : ((31 - j) * 64 + (wave - 4) * 16);
  const int qrow = wrow0 + l15;            // this lane's q row (seq-local)

  // Q fragment (B-operand for S^T, A/B layouts are lane-symmetric)
  bf16x8 qf[2];
  {
    const unsigned short* qp = qkv + (size_t)(b * S_ + qrow) * N3 + h * HD + quad * 8;
    qf[0] = *(const bf16x8*)qp;
    qf[1] = *(const bf16x8*)(qp + 32);
  }

  f32x4 o[4];   // O^T accumulator: d = mb*16+quad*4+r, col = qrow
#pragma unroll
  for (int n = 0; n < 4; n++) o[n] = (f32x4){0.f, 0.f, 0.f, 0.f};
  float lsum = 0.f;

  // K staging: thread -> (row r0s, phys chunk tid&7); phys chunk holds logical
  // chunk (tid&7)^(r0s&7) (XOR swizzle, conflict-free b128 reads)
  const int r0s = tid >> 3;                       // 0..63
  const int gch = ((tid & 7) ^ (r0s & 7)) * 8;
  const unsigned short* kgb = qkv + (size_t)(b * S_ + r0s) * N3 + DM + h * HD + gch;
  // V staging: pure linear copy of the pre-arranged fragment layout
  const unsigned short* vgl = vTn + (size_t)((b * NH + h) * 32) * 4096 + tid * 8;

  const int nt = 32 - j;            // key tiles needed by the high q-tile
  const int nR = (nt + 1) >> 1;     // 128-key rounds

  // stage 64-key tile t into buffer t&3 (2 loads/thread)
  auto STAGE = [&](int t) {
    const int bu = (t & 3) * 4096;
    gload_lds16(&k_sm[bu + tid * 8], kgb + (size_t)t * 64 * N3);
    gload_lds16(&vt_sm[bu + tid * 8], vgl + (size_t)t * 4096);
  };

  // one 64-key sub-tile: QK^T + softmax + pack + PV
  auto SUBTILE = [&](int t) {
    const unsigned short* kb = &k_sm[(t & 3) * 4096];
    const unsigned short* vb = &vt_sm[(t & 3) * 4096];

    f32x4 s[4];
#pragma unroll
    for (int mb = 0; mb < 4; mb++) s[mb] = (f32x4){0.f, 0.f, 0.f, 0.f};
    __builtin_amdgcn_s_setprio(1);
#pragma unroll
    for (int mb = 0; mb < 4; mb++) {
      const int ro = (mb * 16 + l15) * 64;
      bf16x8 kf0 = *(const bf16x8*)&kb[ro + ((quad ^ sw) << 3)];
      bf16x8 kf1 = *(const bf16x8*)&kb[ro + (((4 + quad) ^ sw) << 3)];
      s[mb] = __builtin_amdgcn_mfma_f32_16x16x32_bf16(kf0, qf[0], s[mb], 0, 0, 0);
      s[mb] = __builtin_amdgcn_mfma_f32_16x16x32_bf16(kf1, qf[1], s[mb], 0, 0, 0);
    }
    __builtin_amdgcn_s_setprio(0);

    // P = exp2(S) (scale pre-folded); mask only on the diagonal tile
    if (t * 64 + 63 <= wrow0) {
#pragma unroll
      for (int mb = 0; mb < 4; mb++)
#pragma unroll
        for (int r = 0; r < 4; r++)
          s[mb][r] = exp2f(s[mb][r]);
    } else {
      const int kq0 = t * 64 + quad * 4;
#pragma unroll
      for (int mb = 0; mb < 4; mb++)
#pragma unroll
        for (int r = 0; r < 4; r++) {
          const float e = exp2f(s[mb][r]);
          s[mb][r] = (kq0 + mb * 16 + r <= qrow) ? e : 0.f;
        }
    }
#pragma unroll
    for (int mb = 0; mb < 4; mb++)
      lsum += (s[mb][0] + s[mb][1]) + (s[mb][2] + s[mb][3]);

    // pack: pk[ks] = keys (ks*16+quad*4+0..3) = PV B-frag (cvt_pk, RTNE)
    int pk[4][2];
#pragma unroll
    for (int mb = 0; mb < 4; mb++) {
      pk[mb][0] = cvtpk(s[mb][0], s[mb][1]);
      pk[mb][1] = cvtpk(s[mb][2], s[mb][3]);
    }

    // PV: O^T[d][q] += V^T[d][k] P^T[k][q] via 16x16x16
    __builtin_amdgcn_s_setprio(1);
#pragma unroll
    for (int pp = 0; pp < 2; pp++) {
      i32x2 wlo, whi;
      wlo.x = pk[2 * pp][0];     wlo.y = pk[2 * pp][1];
      whi.x = pk[2 * pp + 1][0]; whi.y = pk[2 * pp + 1][1];
      const bf16x4 blo = __builtin_bit_cast(bf16x4, wlo);
      const bf16x4 bhi = __builtin_bit_cast(bf16x4, whi);
#pragma unroll
      for (int mb = 0; mb < 4; mb++) {
        const bf16x8 vv =
            *(const bf16x8*)&vb[(pp * 256 + mb * 64 + l15 * 4 + quad) * 8];
        bf16x4 alo, ahi;
#pragma unroll
        for (int i = 0; i < 4; i++) { alo[i] = vv[i]; ahi[i] = vv[i + 4]; }
        o[mb] = mfma16(alo, blo, o[mb]);
        o[mb] = mfma16(ahi, bhi, o[mb]);
      }
    }
    __builtin_amdgcn_s_setprio(0);
  };

  // prologue: stage round 0 (tiles 0,1)
  STAGE(0);
  if (1 < nt) STAGE(1);

  for (int r = 0; r < nR; r++) {
    const int t0 = 2 * r, t1 = 2 * r + 1;
    asm volatile("s_waitcnt vmcnt(0)" ::: "memory");
    __builtin_amdgcn_s_barrier();
    __builtin_amdgcn_sched_barrier(0);
    if (r + 1 < nR) {
      STAGE(t0 + 2);
      if (t1 + 2 < nt) STAGE(t1 + 2);
    }
    if (t0 * 64 <= wrow0 + 15) SUBTILE(t0);
    if (t1 < nt && t1 * 64 <= wrow0 + 15) SUBTILE(t1);
  }

  // drain any straggler staging writes before workgroup teardown
  asm volatile("s_waitcnt vmcnt(0)" ::: "memory");

  // normalize + write (O^T: lane has 4 consecutive d per mb for its qrow)
  float l = lsum;
  l += __shfl_xor(l, 16);
  l += __shfl_xor(l, 32);
  const float inv = 1.0f / l;
  const size_t grow = (size_t)(b * S_ + qrow);
#pragma unroll
  for (int mb = 0; mb < 4; mb++) {
    ushort4 w;
    w.x = f2bf(o[mb][0] * inv);
    w.y = f2bf(o[mb][1] * inv);
    w.z = f2bf(o[mb][2] * inv);
    w.w = f2bf(o[mb][3] * inv);
    *(ushort4*)&attnout[grow * DM + h * HD + mb * 16 + quad * 4] = w;
  }
}

// ---------------------------------------------------------------------------
extern "C" void kernel_launch(void* const* d_in, const int* in_sizes, int n_in,
                              void* d_out, int out_size, void* d_ws, size_t ws_size,
                              hipStream_t stream) {
  const float* query = (const float*)d_in[0];   // [4096][1024]
  const float* w_in  = (const float*)d_in[1];   // [1024][3072]
  const float* w_out = (const float*)d_in[2];   // [1024][1024]
  float* out = (float*)d_out;                   // [4096][1024] fp32

  char* ws = (char*)d_ws;
  // lifetimes: qbf prep->gemm1; w_in_t prep->gemm1; w_out_t prep->gemm2;
  // qkv(Q,K) gemm1->attn; vTn gemm1->attn; attnout attn->gemm2.
  unsigned short* qbf     = (unsigned short*)(ws);                 // 8 MB
  unsigned short* attn    = (unsigned short*)(ws);                 // 8 MB (aliases qbf, dead after gemm1)
  unsigned short* w_in_t  = (unsigned short*)(ws + 8388608);       // 6 MB [3072][1024]
  unsigned short* w_out_t = (unsigned short*)(ws + 14680064);      // 2 MB [1024][1024]
  unsigned short* qkv     = (unsigned short*)(ws + 16777216);      // 24 MB [4096][3072] (V third unused)
  unsigned short* vTn     = (unsigned short*)(ws + 41943040);      // 8 MB PV-fragment layout

  // 1. prep: query->bf16, w_in^T (Q-cols pre-scaled by 0.125*log2e), w_out^T
  prep<<<dim3(8192), dim3(256), 0, stream>>>(query, w_in, w_out, qbf, w_in_t, w_out_t);
  // 2. qkv = query @ W_in; V slice written directly in vTn fragment layout
  gemm_qkv<<<dim3(N3 / 128, M_ / 128), dim3(256), 0, stream>>>(qbf, w_in_t, qkv, vTn);
  // 3. fused causal attention -> attn [4096][1024] bf16
  attn_fused13<<<dim3(16, NH, B_), dim3(512), 0, stream>>>(qkv, vTn, attn);
  // 4. out = attn @ W_out   [4096][1024] fp32 (64x128 tiles, 2 blocks/CU)
  gemm_abt_64<<<dim3(DM / 128, M_ / 64), dim3(256), 0, stream>>>(attn, w_out_t, out, M_, DM, DM);
}

// Round 14
// 188.881 us; speedup vs baseline: 1.0477x; 1.0477x over previous
//
#include <hip/hip_runtime.h>

// ---------------------------------------------------------------------------
// MultiHeadedAttention: B=2, S=2048, Dm=1024, H=16, hd=64
// R17: revert R16's GEMM dbuf (regressed via LDS-occupancy loss; implicit
// multi-block overlap already hid staging latency) -> R15 single-buffer
// bodies, + T1 chunked XCD swizzle on BOTH GEMMs:
//  - gemm_qkv FETCH=40MB vs 14.5MB ideal: x-major dispatch scatters the 8
//    blocks sharing an A-panel across 8 XCDs -> 8x A refetch. Chunked remap
//    (768=8x96): each XCD gets 4 M-rows x all N-tiles, A-panels L2-resident.
//  - gemm2 (512=8x64): per-XCD working set (A 1MB + B 2MB) fits 4MB L2.
//  - prep / attn_fused13 byte-identical to R15 (verified; attn ~47us)
// ---------------------------------------------------------------------------

typedef __bf16 bf16x8 __attribute__((ext_vector_type(8)));
typedef __bf16 bf16x4 __attribute__((ext_vector_type(4)));
typedef short s16x4 __attribute__((ext_vector_type(4)));
typedef float f32x4 __attribute__((ext_vector_type(4)));
typedef int i32x2 __attribute__((ext_vector_type(2)));

#define B_   2
#define S_   2048
#define DM   1024
#define NH   16
#define HD   64
#define N3   3072
#define M_   4096   // B_*S_

// 0.125 (1/sqrt(64)) * log2(e) -- folded into W_in Q-columns on host side
#define SCALE_LOG2E 0.180336884f

__device__ __forceinline__ unsigned short f2bf(float f) {
  unsigned int u = __float_as_uint(f);
  u += 0x7fffu + ((u >> 16) & 1u);   // round-to-nearest-even
  return (unsigned short)(u >> 16);
}

__device__ __forceinline__ void gload_lds16(void* lds, const void* g) {
  __builtin_amdgcn_global_load_lds(
      (__attribute__((address_space(1))) void*)g,
      (__attribute__((address_space(3))) void*)lds, 16, 0, 0);
}

// 16x16x16 bf16 MFMA: builtin name differs across ROCm versions
__device__ __forceinline__ f32x4 mfma16(bf16x4 a, bf16x4 b, f32x4 c) {
#if __has_builtin(__builtin_amdgcn_mfma_f32_16x16x16_bf16)
  return __builtin_amdgcn_mfma_f32_16x16x16_bf16(a, b, c, 0, 0, 0);
#else
  return __builtin_amdgcn_mfma_f32_16x16x16bf16_1k(
      __builtin_bit_cast(s16x4, a), __builtin_bit_cast(s16x4, b), c, 0, 0, 0);
#endif
}

// packed f32 pair -> bf16x2 in one VALU op (RTNE), lo=s0 hi=s1
__device__ __forceinline__ int cvtpk(float s0, float s1) {
  int r;
  asm("v_cvt_pk_bf16_f32 %0, %1, %2" : "=v"(r) : "v"(s0), "v"(s1));
  return r;
}

// ---------------- prep: qbf convert + both weight transposes ---------------
// grid 8192 x 256thr: [0,4096) qbf; [4096,7168) w_in^T (scaled); rest w_out^T
__global__ __launch_bounds__(256) void prep(
    const float* __restrict__ query, const float* __restrict__ w_in,
    const float* __restrict__ w_out, unsigned short* __restrict__ qbf,
    unsigned short* __restrict__ w_in_t, unsigned short* __restrict__ w_out_t) {
  __shared__ float tile[32][33];
  const int bx = blockIdx.x;
  const int t = threadIdx.x;
  if (bx < 4096) {                       // query f32 -> bf16, 1024 elems/block
    const int i = bx * 256 + t;
    const float4 v = ((const float4*)query)[i];
    ushort4 o;
    o.x = f2bf(v.x); o.y = f2bf(v.y); o.z = f2bf(v.z); o.w = f2bf(v.w);
    *(ushort4*)(&qbf[(size_t)i * 4]) = o;
    return;
  }
  // 32x32 transpose tasks (tx = t&31, ty = t>>5; 8 rows per pass)
  const int tx = t & 31, ty = t >> 5;
  const float* in;
  unsigned short* out;
  int R, C, bxx, bxy, scale_rows;
  if (bx < 4096 + 3072) {                // w_in [1024][3072] -> [3072][1024]
    const int id = bx - 4096;
    in = w_in; out = w_in_t; R = DM; C = N3;
    bxx = id % 96; bxy = id / 96; scale_rows = DM;
  } else {                               // w_out [1024][1024] -> [1024][1024]
    const int id = bx - 7168;
    in = w_out; out = w_out_t; R = DM; C = DM;
    bxx = id & 31; bxy = id >> 5; scale_rows = 0;
  }
  const int x = bxx * 32 + tx;
  const int y0 = bxy * 32;
#pragma unroll
  for (int j = 0; j < 32; j += 8)
    tile[ty + j][tx] = in[(size_t)(y0 + ty + j) * C + x];
  __syncthreads();
  const int ox = y0 + tx;
  const int oy0 = bxx * 32;
#pragma unroll
  for (int j = 0; j < 32; j += 8) {
    const int orow = oy0 + ty + j;
    float v = tile[tx][ty + j];
    if (orow < scale_rows) v *= SCALE_LOG2E;
    out[(size_t)orow * R + ox] = f2bf(v);
  }
}

// ------- GEMM1: qkv = A @ Bt^T; V-slice written in vTn fragment layout -----
// Single-buffer 2-barrier loop (R15-verified) + T1 chunked XCD swizzle
// (768 blocks = 8 XCD x 96: each XCD gets 4 M-rows x all 24 N-tiles).
// C cols [0,2048) -> qkv row-major bf16 (Q,K). Cols [2048,3072) -> vTn.
__global__ __launch_bounds__(256) void gemm_qkv(
    const unsigned short* __restrict__ A, const unsigned short* __restrict__ Bt,
    unsigned short* __restrict__ qkv, unsigned short* __restrict__ vTn) {
  __shared__ __align__(16) unsigned short a_sm[128 * 32];
  __shared__ __align__(16) unsigned short b_sm[128 * 32];
  const int tid = threadIdx.x;
  const int lane = tid & 63, wave = tid >> 6;
  const int quad = lane >> 4, l15 = lane & 15;
  // chunked XCD swizzle: flat p -> lg; XCD x owns lg in [x*96, x*96+96)
  const int p = blockIdx.x + blockIdx.y * 24;
  const int lg = (p & 7) * 96 + (p >> 3);
  const int bxx = lg % 24, byy = lg / 24;
  const int row0 = byy * 128, col0 = bxx * 128;
  const int wm = (wave >> 1) * 64, wn = (wave & 1) * 64;
  const int K = DM;

  f32x4 acc[4][4];
#pragma unroll
  for (int i = 0; i < 4; i++)
#pragma unroll
    for (int j = 0; j < 4; j++) acc[i][j] = (f32x4){0.f, 0.f, 0.f, 0.f};

  const int e0 = tid * 8;

  for (int k0 = 0; k0 < K; k0 += 32) {
    __syncthreads();
#pragma unroll
    for (int i = 0; i < 2; i++) {
      int e = e0 + i * 2048;
      int r = e >> 5, c = e & 31;
      gload_lds16(&a_sm[e], &A[(size_t)(row0 + r) * K + k0 + c]);
      gload_lds16(&b_sm[e], &Bt[(size_t)(col0 + r) * K + k0 + c]);
    }
    __syncthreads();

    bf16x8 af[4], bfb[4];
#pragma unroll
    for (int i = 0; i < 4; i++) {
      af[i]  = *(const bf16x8*)&a_sm[(wm + i * 16 + l15) * 32 + quad * 8];
      bfb[i] = *(const bf16x8*)&b_sm[(wn + i * 16 + l15) * 32 + quad * 8];
    }
#pragma unroll
    for (int i = 0; i < 4; i++)
#pragma unroll
      for (int j = 0; j < 4; j++)
        acc[i][j] = __builtin_amdgcn_mfma_f32_16x16x32_bf16(af[i], bfb[j], acc[i][j], 0, 0, 0);
  }

  if (col0 + wn < 2 * DM) {
    // Q/K slices: row-major bf16 into qkv
#pragma unroll
    for (int i = 0; i < 4; i++) {
#pragma unroll
      for (int j = 0; j < 4; j++) {
#pragma unroll
        for (int r = 0; r < 4; r++) {
          const int row = row0 + wm + i * 16 + quad * 4 + r;
          const int col = col0 + wn + j * 16 + l15;
          qkv[(size_t)row * N3 + col] = f2bf(acc[i][j][r]);
        }
      }
    }
  } else {
    // V slice: write vTn fragment layout directly (one ushort4 per (i,j))
    const int head = (col0 + wn - 2 * DM) >> 6;   // wave-uniform
#pragma unroll
    for (int i = 0; i < 4; i++) {
      const int row = row0 + wm + i * 16 + quad * 4;   // token of r=0
      const int b = row >> 11;
      const int srow = row & 2047;
      const int kt = srow >> 6;
      const int s = srow & 63;
      const int pp = s >> 5, half = (s >> 4) & 1, q = (s >> 2) & 3;
      const size_t base = (size_t)((b * NH + head) * 32 + kt) * 4096;
#pragma unroll
      for (int j = 0; j < 4; j++) {
        const int d = j * 16 + l15;
        ushort4 w;
        w.x = f2bf(acc[i][j][0]);
        w.y = f2bf(acc[i][j][1]);
        w.z = f2bf(acc[i][j][2]);
        w.w = f2bf(acc[i][j][3]);
        *(ushort4*)&vTn[base + (size_t)(pp * 256 + d * 4 + q) * 8 + half * 4] = w;
      }
    }
  }
}

// ---------------- GEMM 64x128 (fp32 out), single-buffer + T1 swizzle -------
// grid (8,64) = 512 blocks = 8 XCD x 64: each XCD gets 8 M-rows x all 8
// N-tiles -> per-XCD working set (A 1MB + B 2MB) fits L2.
__global__ __launch_bounds__(256) void gemm_abt_64(
    const unsigned short* __restrict__ A, const unsigned short* __restrict__ Bt,
    float* __restrict__ C, int M, int N, int K) {
  __shared__ __align__(16) unsigned short a_sm[64 * 32];    // 4KB
  __shared__ __align__(16) unsigned short b_sm[128 * 32];   // 8KB
  const int tid = threadIdx.x;
  const int lane = tid & 63, wave = tid >> 6;
  const int quad = lane >> 4, l15 = lane & 15;
  const int p = blockIdx.x + (blockIdx.y << 3);
  const int lg = (p & 7) * 64 + (p >> 3);
  const int row0 = (lg >> 3) * 64, col0 = (lg & 7) * 128;
  const int wn = wave * 32;

  f32x4 acc[4][2];
#pragma unroll
  for (int i = 0; i < 4; i++)
#pragma unroll
    for (int j = 0; j < 2; j++) acc[i][j] = (f32x4){0.f, 0.f, 0.f, 0.f};

  const int e0 = tid * 8;

  for (int k0 = 0; k0 < K; k0 += 32) {
    __syncthreads();
    {
      const int r = e0 >> 5, c = e0 & 31;
      gload_lds16(&a_sm[e0], &A[(size_t)(row0 + r) * K + k0 + c]);
    }
#pragma unroll
    for (int i = 0; i < 2; i++) {
      int e = e0 + i * 2048;
      int r = e >> 5, c = e & 31;
      gload_lds16(&b_sm[e], &Bt[(size_t)(col0 + r) * K + k0 + c]);
    }
    __syncthreads();

    bf16x8 af[4], bfb[2];
#pragma unroll
    for (int i = 0; i < 4; i++)
      af[i] = *(const bf16x8*)&a_sm[(i * 16 + l15) * 32 + quad * 8];
#pragma unroll
    for (int j = 0; j < 2; j++)
      bfb[j] = *(const bf16x8*)&b_sm[(wn + j * 16 + l15) * 32 + quad * 8];
#pragma unroll
    for (int i = 0; i < 4; i++)
#pragma unroll
      for (int j = 0; j < 2; j++)
        acc[i][j] = __builtin_amdgcn_mfma_f32_16x16x32_bf16(af[i], bfb[j], acc[i][j], 0, 0, 0);
  }

#pragma unroll
  for (int i = 0; i < 4; i++) {
#pragma unroll
    for (int j = 0; j < 2; j++) {
#pragma unroll
      for (int r = 0; r < 4; r++) {
        const int row = row0 + i * 16 + quad * 4 + r;
        const int col = col0 + wn + j * 16 + l15;
        C[(size_t)row * N + col] = acc[i][j][r];
      }
    }
  }
}

// ---------------- fused causal attention v13 (R15-verified) ----------------
// grid (16, NH, B) = 512 blocks, 512 threads (8 waves).
// T1 chunked XCD swizzle; KVBLK=128 rounds; 4 LDS buffers; prefetch
// distance 1 round; vmcnt(0) + raw s_barrier per round.
__global__ __launch_bounds__(512, 4) void attn_fused13(
    const unsigned short* __restrict__ qkv,
    const unsigned short* __restrict__ vTn,
    unsigned short* __restrict__ attnout) {
  // chunked XCD swizzle (bijective: 512 blocks = 8 XCD x 64)
  const int p = blockIdx.x + (blockIdx.y << 4) + (blockIdx.z << 8);
  const int lg = ((p & 7) << 6) + (p >> 3);
  const int j = lg & 15;
  const int h = (lg >> 4) & 15;
  const int b = lg >> 8;

  const int tid = threadIdx.x;
  const int lane = tid & 63, wave = tid >> 6;   // wave 0..7
  const int quad = lane >> 4, l15 = lane & 15;
  const int sw = l15 & 7;

  __shared__ __align__(16) unsigned short k_sm[4 * 4096];   // [buf][64 keys][64 d]
  __shared__ __align__(16) unsigned short vt_sm[4 * 4096];  // [buf][512 x 16B units]

  // wave 0..3 -> low q-tile (rows j*64 ..); wave 4..7 -> high tile ((31-j)*64 ..)
  const int wrow0 = (wave < 4) ? (j * 64 + wave * 16)
                               : ((31 - j) * 64 + (wave - 4) * 16);
  const int qrow = wrow0 + l15;            // this lane's q row (seq-local)

  // Q fragment (B-operand for S^T, A/B layouts are lane-symmetric)
  bf16x8 qf[2];
  {
    const unsigned short* qp = qkv + (size_t)(b * S_ + qrow) * N3 + h * HD + quad * 8;
    qf[0] = *(const bf16x8*)qp;
    qf[1] = *(const bf16x8*)(qp + 32);
  }

  f32x4 o[4];   // O^T accumulator: d = mb*16+quad*4+r, col = qrow
#pragma unroll
  for (int n = 0; n < 4; n++) o[n] = (f32x4){0.f, 0.f, 0.f, 0.f};
  float lsum = 0.f;

  // K staging: thread -> (row r0s, phys chunk tid&7); phys chunk holds logical
  // chunk (tid&7)^(r0s&7) (XOR swizzle, conflict-free b128 reads)
  const int r0s = tid >> 3;                       // 0..63
  const int gch = ((tid & 7) ^ (r0s & 7)) * 8;
  const unsigned short* kgb = qkv + (size_t)(b * S_ + r0s) * N3 + DM + h * HD + gch;
  // V staging: pure linear copy of the pre-arranged fragment layout
  const unsigned short* vgl = vTn + (size_t)((b * NH + h) * 32) * 4096 + tid * 8;

  const int nt = 32 - j;            // key tiles needed by the high q-tile
  const int nR = (nt + 1) >> 1;     // 128-key rounds

  // stage 64-key tile t into buffer t&3 (2 loads/thread)
  auto STAGE = [&](int t) {
    const int bu = (t & 3) * 4096;
    gload_lds16(&k_sm[bu + tid * 8], kgb + (size_t)t * 64 * N3);
    gload_lds16(&vt_sm[bu + tid * 8], vgl + (size_t)t * 4096);
  };

  // one 64-key sub-tile: QK^T + softmax + pack + PV
  auto SUBTILE = [&](int t) {
    const unsigned short* kb = &k_sm[(t & 3) * 4096];
    const unsigned short* vb = &vt_sm[(t & 3) * 4096];

    f32x4 s[4];
#pragma unroll
    for (int mb = 0; mb < 4; mb++) s[mb] = (f32x4){0.f, 0.f, 0.f, 0.f};
    __builtin_amdgcn_s_setprio(1);
#pragma unroll
    for (int mb = 0; mb < 4; mb++) {
      const int ro = (mb * 16 + l15) * 64;
      bf16x8 kf0 = *(const bf16x8*)&kb[ro + ((quad ^ sw) << 3)];
      bf16x8 kf1 = *(const bf16x8*)&kb[ro + (((4 + quad) ^ sw) << 3)];
      s[mb] = __builtin_amdgcn_mfma_f32_16x16x32_bf16(kf0, qf[0], s[mb], 0, 0, 0);
      s[mb] = __builtin_amdgcn_mfma_f32_16x16x32_bf16(kf1, qf[1], s[mb], 0, 0, 0);
    }
    __builtin_amdgcn_s_setprio(0);

    // P = exp2(S) (scale pre-folded); mask only on the diagonal tile
    if (t * 64 + 63 <= wrow0) {
#pragma unroll
      for (int mb = 0; mb < 4; mb++)
#pragma unroll
        for (int r = 0; r < 4; r++)
          s[mb][r] = exp2f(s[mb][r]);
    } else {
      const int kq0 = t * 64 + quad * 4;
#pragma unroll
      for (int mb = 0; mb < 4; mb++)
#pragma unroll
        for (int r = 0; r < 4; r++) {
          const float e = exp2f(s[mb][r]);
          s[mb][r] = (kq0 + mb * 16 + r <= qrow) ? e : 0.f;
        }
    }
#pragma unroll
    for (int mb = 0; mb < 4; mb++)
      lsum += (s[mb][0] + s[mb][1]) + (s[mb][2] + s[mb][3]);

    // pack: pk[ks] = keys (ks*16+quad*4+0..3) = PV B-frag (cvt_pk, RTNE)
    int pk[4][2];
#pragma unroll
    for (int mb = 0; mb < 4; mb++) {
      pk[mb][0] = cvtpk(s[mb][0], s[mb][1]);
      pk[mb][1] = cvtpk(s[mb][2], s[mb][3]);
    }

    // PV: O^T[d][q] += V^T[d][k] P^T[k][q] via 16x16x16
    __builtin_amdgcn_s_setprio(1);
#pragma unroll
    for (int pp = 0; pp < 2; pp++) {
      i32x2 wlo, whi;
      wlo.x = pk[2 * pp][0];     wlo.y = pk[2 * pp][1];
      whi.x = pk[2 * pp + 1][0]; whi.y = pk[2 * pp + 1][1];
      const bf16x4 blo = __builtin_bit_cast(bf16x4, wlo);
      const bf16x4 bhi = __builtin_bit_cast(bf16x4, whi);
#pragma unroll
      for (int mb = 0; mb < 4; mb++) {
        const bf16x8 vv =
            *(const bf16x8*)&vb[(pp * 256 + mb * 64 + l15 * 4 + quad) * 8];
        bf16x4 alo, ahi;
#pragma unroll
        for (int i = 0; i < 4; i++) { alo[i] = vv[i]; ahi[i] = vv[i + 4]; }
        o[mb] = mfma16(alo, blo, o[mb]);
        o[mb] = mfma16(ahi, bhi, o[mb]);
      }
    }
    __builtin_amdgcn_s_setprio(0);
  };

  // prologue: stage round 0 (tiles 0,1)
  STAGE(0);
  if (1 < nt) STAGE(1);

  for (int r = 0; r < nR; r++) {
    const int t0 = 2 * r, t1 = 2 * r + 1;
    asm volatile("s_waitcnt vmcnt(0)" ::: "memory");
    __builtin_amdgcn_s_barrier();
    __builtin_amdgcn_sched_barrier(0);
    if (r + 1 < nR) {
      STAGE(t0 + 2);
      if (t1 + 2 < nt) STAGE(t1 + 2);
    }
    if (t0 * 64 <= wrow0 + 15) SUBTILE(t0);
    if (t1 < nt && t1 * 64 <= wrow0 + 15) SUBTILE(t1);
  }

  // drain any straggler staging writes before workgroup teardown
  asm volatile("s_waitcnt vmcnt(0)" ::: "memory");

  // normalize + write (O^T: lane has 4 consecutive d per mb for its qrow)
  float l = lsum;
  l += __shfl_xor(l, 16);
  l += __shfl_xor(l, 32);
  const float inv = 1.0f / l;
  const size_t grow = (size_t)(b * S_ + qrow);
#pragma unroll
  for (int mb = 0; mb < 4; mb++) {
    ushort4 w;
    w.x = f2bf(o[mb][0] * inv);
    w.y = f2bf(o[mb][1] * inv);
    w.z = f2bf(o[mb][2] * inv);
    w.w = f2bf(o[mb][3] * inv);
    *(ushort4*)&attnout[grow * DM + h * HD + mb * 16 + quad * 4] = w;
  }
}

// ---------------------------------------------------------------------------
extern "C" void kernel_launch(void* const* d_in, const int* in_sizes, int n_in,
                              void* d_out, int out_size, void* d_ws, size_t ws_size,
                              hipStream_t stream) {
  const float* query = (const float*)d_in[0];   // [4096][1024]
  const float* w_in  = (const float*)d_in[1];   // [1024][3072]
  const float* w_out = (const float*)d_in[2];   // [1024][1024]
  float* out = (float*)d_out;                   // [4096][1024] fp32

  char* ws = (char*)d_ws;
  // lifetimes: qbf prep->gemm1; w_in_t prep->gemm1; w_out_t prep->gemm2;
  // qkv(Q,K) gemm1->attn; vTn gemm1->attn; attnout attn->gemm2.
  unsigned short* qbf     = (unsigned short*)(ws);                 // 8 MB
  unsigned short* attn    = (unsigned short*)(ws);                 // 8 MB (aliases qbf, dead after gemm1)
  unsigned short* w_in_t  = (unsigned short*)(ws + 8388608);       // 6 MB [3072][1024]
  unsigned short* w_out_t = (unsigned short*)(ws + 14680064);      // 2 MB [1024][1024]
  unsigned short* qkv     = (unsigned short*)(ws + 16777216);      // 24 MB [4096][3072] (V third unused)
  unsigned short* vTn     = (unsigned short*)(ws + 41943040);      // 8 MB PV-fragment layout

  // 1. prep: query->bf16, w_in^T (Q-cols pre-scaled by 0.125*log2e), w_out^T
  prep<<<dim3(8192), dim3(256), 0, stream>>>(query, w_in, w_out, qbf, w_in_t, w_out_t);
  // 2. qkv = query @ W_in; V slice written directly in vTn fragment layout
  gemm_qkv<<<dim3(N3 / 128, M_ / 128), dim3(256), 0, stream>>>(qbf, w_in_t, qkv, vTn);
  // 3. fused causal attention -> attn [4096][1024] bf16
  attn_fused13<<<dim3(16, NH, B_), dim3(512), 0, stream>>>(qkv, vTn, attn);
  // 4. out = attn @ W_out   [4096][1024] fp32 (64x128 tiles, 2 blocks/CU)
  gemm_abt_64<<<dim3(DM / 128, M_ / 64), dim3(256), 0, stream>>>(attn, w_out_t, out, M_, DM, DM);
}